// Round 11
// baseline (56.206 us; speedup 1.0000x reference)
//
#include <hip/hip_runtime.h>

#define DIM   4096
#define BATCH 8192
// One row per 128-thread block (2 waves). Wave w = e{11}. Thread lane l holds
// e = 2048w + 256j + 4l + i  (j=0..7, i=0..3) -> 8 float4 = 32 data VGPRs.
// Layer L pairs e with e^(1<<L); coeff index c = (4096 - (4096>>L)) + (e >> (L+1)).
//   L0..L1 : within float4 (i axis)        — register FMAs
//   L2..L7 : lane xor 1,2,4,8,16,32       — quad_perm DPP (1,2), ds_swizzle (4),
//                                            row_ror:8 DPP (8), permlane16_swap (16),
//                                            permlane32_swap (32)   [all HW-validated]
//   L8..L10: register index j dist 1,2,4   — register FMAs, scalar (s_load) coeffs
//   L11    : cross-wave (w axis)           — 2-source LDS exchange, ONE barrier
//            (half the b128 traffic of R9's 4-source combine: 16 ops / 32 elements)
// No pack dispatch; stores nontemporal. R1/R3 lesson: no min-waves launch bound.
// Spill tell = WRITE_SIZE > 131072 KB.

#if defined(__has_builtin)
#  if __has_builtin(__builtin_amdgcn_permlane32_swap)
#    define HAVE_PL32 1
#  endif
#  if __has_builtin(__builtin_amdgcn_permlane16_swap)
#    define HAVE_PL16 1
#  endif
#endif
#ifndef HAVE_PL32
#  define HAVE_PL32 0
#endif
#ifndef HAVE_PL16
#  define HAVE_PL16 0
#endif

typedef float f32x4_v __attribute__((ext_vector_type(4)));

__device__ __forceinline__ void store_nt4(float4* p, const float4& v) {
    f32x4_v t; t.x = v.x; t.y = v.y; t.z = v.z; t.w = v.w;
    __builtin_nontemporal_store(t, reinterpret_cast<f32x4_v*>(p));
}

__device__ __forceinline__ void rot2(float& lo, float& hi, float a, float b) {
    float l = lo, h = hi;
    lo = fmaf(a, l,  b * h);   // top =  a*x0 + b*x1
    hi = fmaf(a, h, -b * l);   // bot = -b*x0 + a*x1
}
__device__ __forceinline__ void rot4(float4& lo, float4& hi, float a, float b) {
    rot2(lo.x, hi.x, a, b); rot2(lo.y, hi.y, a, b);
    rot2(lo.z, hi.z, a, b); rot2(lo.w, hi.w, a, b);
}

// Cross-lane xor-M partner fetch on the fastest pipe per M (R6/R8-validated).
template<int M>
__device__ __forceinline__ float pxor(float x, bool hi) {
    int xi = __float_as_int(x);
    if constexpr (M == 1)        // quad_perm [1,0,3,2]
        return __int_as_float(__builtin_amdgcn_update_dpp(0, xi, 0xB1, 0xF, 0xF, true));
    else if constexpr (M == 2)   // quad_perm [2,3,0,1]
        return __int_as_float(__builtin_amdgcn_update_dpp(0, xi, 0x4E, 0xF, 0xF, true));
    else if constexpr (M == 4)   // ds_swizzle BitMode xor 4
        return __int_as_float(__builtin_amdgcn_ds_swizzle(xi, 0x101F));
    else if constexpr (M == 8)   // row_ror:8 within row-of-16 == xor 8
        return __int_as_float(__builtin_amdgcn_update_dpp(0, xi, 0x128, 0xF, 0xF, true));
    else if constexpr (M == 16) {
#if HAVE_PL16
        unsigned xu = (unsigned)xi;
        auto r = __builtin_amdgcn_permlane16_swap(xu, xu, false, false);
        return __uint_as_float(hi ? r[0] : r[1]);
#else
        return __int_as_float(__builtin_amdgcn_ds_swizzle(xi, 0x401F));
#endif
    } else {                     // M == 32
#if HAVE_PL32
        unsigned xu = (unsigned)xi;
        auto r = __builtin_amdgcn_permlane32_swap(xu, xu, false, false);
        return __uint_as_float(hi ? r[0] : r[1]);
#else
        return __shfl_xor(x, 32, 64);
#endif
    }
}

// c = base + (j<<JSH) + (lane>>LSH); UNIF: wave-uniform -> s_load path.
template<int M, int JSH, int LSH, bool UNIF>
__device__ __forceinline__ void shuf_layer(float4 (&v)[8], int lane, int base,
                                           const float* __restrict__ af,
                                           const float* __restrict__ bf) {
    const bool hi = (lane & M) != 0;
    #pragma unroll
    for (int j = 0; j < 8; ++j) {
        int c = base + (j << JSH) + (lane >> LSH);
        if constexpr (UNIF) c = __builtin_amdgcn_readfirstlane(c);
        const float a = af[c], b = bf[c];
        const float sb = hi ? -b : b;   // top: +b*partner ; bot: -b*partner
        v[j].x = fmaf(a, v[j].x, sb * pxor<M>(v[j].x, hi));
        v[j].y = fmaf(a, v[j].y, sb * pxor<M>(v[j].y, hi));
        v[j].z = fmaf(a, v[j].z, sb * pxor<M>(v[j].z, hi));
        v[j].w = fmaf(a, v[j].w, sb * pxor<M>(v[j].w, hi));
    }
}

__global__ __launch_bounds__(128)
void bfly_kernel(const float* __restrict__ x,
                 const float* __restrict__ af,
                 const float* __restrict__ bf,
                 float* __restrict__ out) {
    const int lane = threadIdx.x & 63;
    const int w    = threadIdx.x >> 6;     // wave = e{11}
    const size_t row = blockIdx.x;

    const float4* __restrict__ xr = reinterpret_cast<const float4*>(x + row * DIM) + w * 512;
    float4* __restrict__ orow     = reinterpret_cast<float4*>(out + row * DIM) + w * 512;

    __shared__ float4 xch[2][8][64];   // [wave][j][lane] = 16 KB

    float4 v[8];
    #pragma unroll
    for (int j = 0; j < 8; ++j) v[j] = xr[64 * j + lane];

    // ---- L0 (bs=1): pairs (x,y),(z,w); c = 1024w + 128j + 2*lane (+1) ----
    #pragma unroll
    for (int j = 0; j < 8; ++j) {
        const int c = 1024 * w + 128 * j + 2 * lane;
        float2 aa = *reinterpret_cast<const float2*>(af + c);
        float2 bb = *reinterpret_cast<const float2*>(bf + c);
        rot2(v[j].x, v[j].y, aa.x, bb.x);
        rot2(v[j].z, v[j].w, aa.y, bb.y);
    }

    // ---- L1 (bs=2): pairs (x,z),(y,w); c = 2048 + 512w + 64j + lane ----
    #pragma unroll
    for (int j = 0; j < 8; ++j) {
        const int c = 2048 + 512 * w + 64 * j + lane;
        const float a = af[c], b = bf[c];
        rot2(v[j].x, v[j].z, a, b);
        rot2(v[j].y, v[j].w, a, b);
    }

    // ---- L2..L7: cross-lane layers (DPP / swizzle / permlane) ----
    shuf_layer< 1, 5, 1, false>(v, lane, 3072 + 256 * w, af, bf);  // bs=4
    shuf_layer< 2, 4, 2, false>(v, lane, 3584 + 128 * w, af, bf);  // bs=8
    shuf_layer< 4, 3, 3, false>(v, lane, 3840 +  64 * w, af, bf);  // bs=16
    shuf_layer< 8, 2, 4, false>(v, lane, 3968 +  32 * w, af, bf);  // bs=32
    shuf_layer<16, 1, 5, false>(v, lane, 4032 +  16 * w, af, bf);  // bs=64
    shuf_layer<32, 0, 6, true >(v, lane, 4064 +   8 * w, af, bf);  // bs=128 (uniform)

    // ---- L8 (bs=256): pairs (2k, 2k+1); c = 4080 + 4w + k (uniform) ----
    #pragma unroll
    for (int k = 0; k < 4; ++k) {
        const int c = __builtin_amdgcn_readfirstlane(4080 + 4 * w + k);
        rot4(v[2*k], v[2*k + 1], af[c], bf[c]);
    }
    // ---- L9 (bs=512): pairs (4g+t, 4g+t+2); c = 4088 + 2w + g (uniform) ----
    #pragma unroll
    for (int g = 0; g < 2; ++g) {
        const int c = __builtin_amdgcn_readfirstlane(4088 + 2 * w + g);
        const float a = af[c], b = bf[c];
        rot4(v[4*g],     v[4*g + 2], a, b);
        rot4(v[4*g + 1], v[4*g + 3], a, b);
    }
    // ---- L10 (bs=1024): pairs (t, t+4); c = 4092 + w (uniform) ----
    {
        const int c = __builtin_amdgcn_readfirstlane(4092 + w);
        const float a = af[c], b = bf[c];
        #pragma unroll
        for (int t = 0; t < 4; ++t) rot4(v[t], v[t + 4], a, b);
    }

    // ---- L11 (bs=2048): cross-wave 2-source exchange; c = 4094; ONE barrier ----
    {
        const float A = af[4094], B = bf[4094];
        const float sb = w ? -B : B;   // w=0: A*own + B*partner ; w=1: A*own - B*partner
        #pragma unroll
        for (int j = 0; j < 8; ++j) xch[w][j][lane] = v[j];
        __syncthreads();
        #pragma unroll
        for (int j = 0; j < 8; ++j) {
            float4 p = xch[w ^ 1][j][lane];
            v[j].x = fmaf(A, v[j].x, sb * p.x);
            v[j].y = fmaf(A, v[j].y, sb * p.y);
            v[j].z = fmaf(A, v[j].z, sb * p.z);
            v[j].w = fmaf(A, v[j].w, sb * p.w);
        }
    }

    // ---- Store: nontemporal, coalesced 16B/lane ----
    #pragma unroll
    for (int j = 0; j < 8; ++j) store_nt4(&orow[64 * j + lane], v[j]);
}

extern "C" void kernel_launch(void* const* d_in, const int* in_sizes, int n_in,
                              void* d_out, int out_size, void* d_ws, size_t ws_size,
                              hipStream_t stream) {
    const float* x  = (const float*)d_in[0];
    const float* af = (const float*)d_in[1];
    const float* bf = (const float*)d_in[2];
    float* out      = (float*)d_out;
    (void)d_ws; (void)ws_size;

    hipLaunchKernelGGL(bfly_kernel, dim3(BATCH), dim3(128), 0, stream,
                       x, af, bf, out);
}

// Round 12
// 50.249 us; speedup vs baseline: 1.1186x; 1.1186x over previous
//
#include <hip/hip_runtime.h>

#define DIM   4096
#define BATCH 8192
// Two rows per 512-thread block (8 waves). Waves 0-3 own row 2*bid, waves 4-7 own
// row 2*bid+1. Within a row, wave q owns quarter [1024q, 1024q+1024); thread lane
// holds e = 1024q + 256j + 4*lane + i (j,i=0..3) — R9-validated bit-for-bit.
// Layer L pairs e with e^(1<<L); coeff index c = (4096 - (4096>>L)) + (e >> (L+1)).
//   L0..L1  : within float4 (i axis)        — register FMAs
//   L2..L7  : lane xor 1,2,4,8,16,32        — quad_perm DPP (1,2), ds_swizzle (4),
//                                             row_ror:8 DPP (8), permlane16_swap (16),
//                                             permlane32_swap (32)   [HW-validated]
//   L8..L9  : register index j distance 1,2 — register FMAs, scalar (s_load) coeffs
//   L10+L11 : cross-wave, FUSED 4-source combine (R3/R6/R9-verified), ONE barrier.
// R11 change vs R9: 512-thread blocks -> 4 blocks/CU x 8 waves = 32 waves/CU (cap),
// vs R9's measured 75%. Per-thread code identical. Stores nontemporal.
// Spill tell = WRITE_SIZE > 131072 KB.

#if defined(__has_builtin)
#  if __has_builtin(__builtin_amdgcn_permlane32_swap)
#    define HAVE_PL32 1
#  endif
#  if __has_builtin(__builtin_amdgcn_permlane16_swap)
#    define HAVE_PL16 1
#  endif
#endif
#ifndef HAVE_PL32
#  define HAVE_PL32 0
#endif
#ifndef HAVE_PL16
#  define HAVE_PL16 0
#endif

typedef float f32x4_v __attribute__((ext_vector_type(4)));

__device__ __forceinline__ void store_nt4(float4* p, const float4& v) {
    f32x4_v t; t.x = v.x; t.y = v.y; t.z = v.z; t.w = v.w;
    __builtin_nontemporal_store(t, reinterpret_cast<f32x4_v*>(p));
}

__device__ __forceinline__ void rot2(float& lo, float& hi, float a, float b) {
    float l = lo, h = hi;
    lo = fmaf(a, l,  b * h);   // top =  a*x0 + b*x1
    hi = fmaf(a, h, -b * l);   // bot = -b*x0 + a*x1
}

// Cross-lane xor-M partner fetch on the fastest pipe per M (R6/R8-validated).
template<int M>
__device__ __forceinline__ float pxor(float x, bool hi) {
    int xi = __float_as_int(x);
    if constexpr (M == 1)        // quad_perm [1,0,3,2]
        return __int_as_float(__builtin_amdgcn_update_dpp(0, xi, 0xB1, 0xF, 0xF, true));
    else if constexpr (M == 2)   // quad_perm [2,3,0,1]
        return __int_as_float(__builtin_amdgcn_update_dpp(0, xi, 0x4E, 0xF, 0xF, true));
    else if constexpr (M == 4)   // ds_swizzle BitMode xor 4
        return __int_as_float(__builtin_amdgcn_ds_swizzle(xi, 0x101F));
    else if constexpr (M == 8)   // row_ror:8 within row-of-16 == xor 8
        return __int_as_float(__builtin_amdgcn_update_dpp(0, xi, 0x128, 0xF, 0xF, true));
    else if constexpr (M == 16) {
#if HAVE_PL16
        unsigned xu = (unsigned)xi;
        auto r = __builtin_amdgcn_permlane16_swap(xu, xu, false, false);
        return __uint_as_float(hi ? r[0] : r[1]);
#else
        return __int_as_float(__builtin_amdgcn_ds_swizzle(xi, 0x401F));
#endif
    } else {                     // M == 32
#if HAVE_PL32
        unsigned xu = (unsigned)xi;
        auto r = __builtin_amdgcn_permlane32_swap(xu, xu, false, false);
        return __uint_as_float(hi ? r[0] : r[1]);
#else
        return __shfl_xor(x, 32, 64);
#endif
    }
}

// UNIF: c is wave-uniform -> readfirstlane so the compiler emits s_load (SMEM).
template<int M, int JSH, int LSH, bool UNIF>
__device__ __forceinline__ void shuf_layer(float4 (&v)[4], int lane, int base,
                                           const float* __restrict__ af,
                                           const float* __restrict__ bf) {
    const bool hi = (lane & M) != 0;
    #pragma unroll
    for (int j = 0; j < 4; ++j) {
        int c = base + (j << JSH) + (lane >> LSH);
        if constexpr (UNIF) c = __builtin_amdgcn_readfirstlane(c);
        const float a = af[c], b = bf[c];
        const float sb = hi ? -b : b;   // top: +b*partner ; bot: -b*partner
        v[j].x = fmaf(a, v[j].x, sb * pxor<M>(v[j].x, hi));
        v[j].y = fmaf(a, v[j].y, sb * pxor<M>(v[j].y, hi));
        v[j].z = fmaf(a, v[j].z, sb * pxor<M>(v[j].z, hi));
        v[j].w = fmaf(a, v[j].w, sb * pxor<M>(v[j].w, hi));
    }
}

__global__ __launch_bounds__(512)
void bfly_kernel(const float* __restrict__ x,
                 const float* __restrict__ af,
                 const float* __restrict__ bf,
                 float* __restrict__ out) {
    const int lane = threadIdx.x & 63;
    const int ww   = threadIdx.x >> 6;     // wave in block: 0..7
    const int r    = ww >> 2;              // row in block: 0,1
    const int q    = ww & 3;               // wave index = row quarter
    const size_t row = (size_t)blockIdx.x * 2 + r;

    const float4* __restrict__ xr = reinterpret_cast<const float4*>(x + row * DIM) + q * 256;
    float4* __restrict__ orow     = reinterpret_cast<float4*>(out + row * DIM) + q * 256;

    __shared__ float4 xch[2][4][4][64];   // [rowInBlock][wave][j][lane] = 32 KB

    float4 v[4];
    #pragma unroll
    for (int j = 0; j < 4; ++j) v[j] = xr[64 * j + lane];

    // ---- L0 (bs=1): pairs (x,y),(z,w); c0 = 512q + 128j + 2*lane, c0+1 ----
    #pragma unroll
    for (int j = 0; j < 4; ++j) {
        const int c = 512 * q + 128 * j + 2 * lane;
        float2 aa = *reinterpret_cast<const float2*>(af + c);
        float2 bb = *reinterpret_cast<const float2*>(bf + c);
        rot2(v[j].x, v[j].y, aa.x, bb.x);
        rot2(v[j].z, v[j].w, aa.y, bb.y);
    }

    // ---- L1 (bs=2): pairs (x,z),(y,w); c = 2048 + 256q + 64j + lane ----
    #pragma unroll
    for (int j = 0; j < 4; ++j) {
        const int c = 2048 + 256 * q + 64 * j + lane;
        const float a = af[c], b = bf[c];
        rot2(v[j].x, v[j].z, a, b);
        rot2(v[j].y, v[j].w, a, b);
    }

    // ---- L2..L7: cross-lane layers (DPP / swizzle / permlane) ----
    shuf_layer< 1, 5, 1, false>(v, lane, 3072 + 128 * q, af, bf);  // bs=4
    shuf_layer< 2, 4, 2, false>(v, lane, 3584 +  64 * q, af, bf);  // bs=8
    shuf_layer< 4, 3, 3, false>(v, lane, 3840 +  32 * q, af, bf);  // bs=16
    shuf_layer< 8, 2, 4, false>(v, lane, 3968 +  16 * q, af, bf);  // bs=32
    shuf_layer<16, 1, 5, false>(v, lane, 4032 +   8 * q, af, bf);  // bs=64
    shuf_layer<32, 0, 6, true >(v, lane, 4064 +   4 * q, af, bf);  // bs=128 (uniform)

    // ---- L8 (bs=256): pairs (0,1),(2,3); c = 4080 + 2q + k (uniform -> s_load) ----
    #pragma unroll
    for (int k = 0; k < 2; ++k) {
        const int c = __builtin_amdgcn_readfirstlane(4080 + 2 * q + k);
        const float a = af[c], b = bf[c];
        rot2(v[2*k].x, v[2*k+1].x, a, b);
        rot2(v[2*k].y, v[2*k+1].y, a, b);
        rot2(v[2*k].z, v[2*k+1].z, a, b);
        rot2(v[2*k].w, v[2*k+1].w, a, b);
    }
    // ---- L9 (bs=512): pairs (0,2),(1,3); c = 4088 + q (uniform) ----
    {
        const int c = __builtin_amdgcn_readfirstlane(4088 + q);
        const float a = af[c], b = bf[c];
        #pragma unroll
        for (int j = 0; j < 2; ++j) {
            rot2(v[j].x, v[j+2].x, a, b);
            rot2(v[j].y, v[j+2].y, a, b);
            rot2(v[j].z, v[j+2].z, a, b);
            rot2(v[j].w, v[j+2].w, a, b);
        }
    }

    // ---- L10+L11 fused: one 4-source combine across the row's 4 waves, ONE barrier --
    // (R3/R6/R9-verified algebra.) u = w0*v + w1*v(q^1) + w2*v(q^2) + w3*v(q^3).
    {
        const float a0 = af[4092], b0 = bf[4092];   // e11=0  (constant idx -> s_load)
        const float a1 = af[4093], b1 = bf[4093];   // e11=1
        const float A  = af[4094], B  = bf[4094];
        const int h11 = q >> 1, h10 = q & 1;
        const float aO = h11 ? a1 : a0, bO = h11 ? b1 : b0;
        const float aX = h11 ? a0 : a1, bX = h11 ? b0 : b1;
        const float phX = h11 ? -B : B;
        const float w0 = A * aO;
        const float w1 = A * (h10 ? -bO : bO);
        const float w2 = phX * aX;
        const float w3 = phX * (h10 ? -bX : bX);
        const int q1 = q ^ 1, q2 = q ^ 2, q3 = q ^ 3;

        #pragma unroll
        for (int j = 0; j < 4; ++j) xch[r][q][j][lane] = v[j];
        __syncthreads();
        #pragma unroll
        for (int j = 0; j < 4; ++j) {
            float4 e1 = xch[r][q1][j][lane];
            float4 e2 = xch[r][q2][j][lane];
            float4 e3 = xch[r][q3][j][lane];
            float4 a;
            a.x = fmaf(w3, e3.x, fmaf(w2, e2.x, fmaf(w1, e1.x, w0 * v[j].x)));
            a.y = fmaf(w3, e3.y, fmaf(w2, e2.y, fmaf(w1, e1.y, w0 * v[j].y)));
            a.z = fmaf(w3, e3.z, fmaf(w2, e2.z, fmaf(w1, e1.z, w0 * v[j].z)));
            a.w = fmaf(w3, e3.w, fmaf(w2, e2.w, fmaf(w1, e1.w, w0 * v[j].w)));
            v[j] = a;
        }
    }

    // ---- Store: nontemporal, coalesced 16B/lane ----
    #pragma unroll
    for (int j = 0; j < 4; ++j) store_nt4(&orow[64 * j + lane], v[j]);
}

extern "C" void kernel_launch(void* const* d_in, const int* in_sizes, int n_in,
                              void* d_out, int out_size, void* d_ws, size_t ws_size,
                              hipStream_t stream) {
    const float* x  = (const float*)d_in[0];
    const float* af = (const float*)d_in[1];
    const float* bf = (const float*)d_in[2];
    float* out      = (float*)d_out;
    (void)d_ws; (void)ws_size;

    hipLaunchKernelGGL(bfly_kernel, dim3(BATCH / 2), dim3(512), 0, stream,
                       x, af, bf, out);
}

// Round 13
// 49.326 us; speedup vs baseline: 1.1395x; 1.0187x over previous
//
#include <hip/hip_runtime.h>

#define DIM   4096
#define BATCH 8192
// One row per 256-thread block (R9-champion structure, bit-identical except pxor<4>).
// Wave q owns quarter [1024q, 1024q+1024); lane holds e = 1024q + 256j + 4*lane + i.
// Layer L pairs e with e^(1<<L); coeff index c = (4096 - (4096>>L)) + (e >> (L+1)).
//   L0..L1  : within float4 (i axis)        — register FMAs
//   L2..L7  : lane xor 1,2,4,8,16,32        — quad_perm DPP (1,2),
//                                             row_half_mirror+quad_perm DPP chain (4),
//                                             row_ror:8 DPP (8), permlane16_swap (16),
//                                             permlane32_swap (32)
//             -> R12: xor4 moved OFF the LDS pipe (was the last ds_swizzle);
//                the ONLY remaining LDS ops are the 16 b128 exchange ops in L10+11.
//   L8..L9  : register index j distance 1,2 — register FMAs, scalar (s_load) coeffs
//   L10+L11 : cross-wave, FUSED 4-source combine (R3/R6/R9-verified), ONE barrier.
// No pack dispatch; stores nontemporal. Spill tell = WRITE_SIZE > 131072 KB.

#if defined(__has_builtin)
#  if __has_builtin(__builtin_amdgcn_permlane32_swap)
#    define HAVE_PL32 1
#  endif
#  if __has_builtin(__builtin_amdgcn_permlane16_swap)
#    define HAVE_PL16 1
#  endif
#endif
#ifndef HAVE_PL32
#  define HAVE_PL32 0
#endif
#ifndef HAVE_PL16
#  define HAVE_PL16 0
#endif

typedef float f32x4_v __attribute__((ext_vector_type(4)));

__device__ __forceinline__ void store_nt4(float4* p, const float4& v) {
    f32x4_v t; t.x = v.x; t.y = v.y; t.z = v.z; t.w = v.w;
    __builtin_nontemporal_store(t, reinterpret_cast<f32x4_v*>(p));
}

__device__ __forceinline__ void rot2(float& lo, float& hi, float a, float b) {
    float l = lo, h = hi;
    lo = fmaf(a, l,  b * h);   // top =  a*x0 + b*x1
    hi = fmaf(a, h, -b * l);   // bot = -b*x0 + a*x1
}

// Cross-lane xor-M partner fetch, all on VALU/DPP pipes (R6/R8-validated + R12 xor4).
template<int M>
__device__ __forceinline__ float pxor(float x, bool hi) {
    int xi = __float_as_int(x);
    if constexpr (M == 1)        // quad_perm [1,0,3,2]
        return __int_as_float(__builtin_amdgcn_update_dpp(0, xi, 0xB1, 0xF, 0xF, true));
    else if constexpr (M == 2)   // quad_perm [2,3,0,1]
        return __int_as_float(__builtin_amdgcn_update_dpp(0, xi, 0x4E, 0xF, 0xF, true));
    else if constexpr (M == 4) { // row_half_mirror (l^7) then quad_perm[3,2,1,0] (l^3)
        int t = __builtin_amdgcn_update_dpp(0, xi, 0x141, 0xF, 0xF, true);  // x[l^7]
        return __int_as_float(__builtin_amdgcn_update_dpp(0, t, 0x1B, 0xF, 0xF, true)); // x[l^4]
    }
    else if constexpr (M == 8)   // row_ror:8 within row-of-16 == xor 8
        return __int_as_float(__builtin_amdgcn_update_dpp(0, xi, 0x128, 0xF, 0xF, true));
    else if constexpr (M == 16) {
#if HAVE_PL16
        unsigned xu = (unsigned)xi;
        auto r = __builtin_amdgcn_permlane16_swap(xu, xu, false, false);
        return __uint_as_float(hi ? r[0] : r[1]);
#else
        return __int_as_float(__builtin_amdgcn_ds_swizzle(xi, 0x401F));
#endif
    } else {                     // M == 32
#if HAVE_PL32
        unsigned xu = (unsigned)xi;
        auto r = __builtin_amdgcn_permlane32_swap(xu, xu, false, false);
        return __uint_as_float(hi ? r[0] : r[1]);
#else
        return __shfl_xor(x, 32, 64);
#endif
    }
}

// UNIF: c is wave-uniform -> readfirstlane so the compiler emits s_load (SMEM).
template<int M, int JSH, int LSH, bool UNIF>
__device__ __forceinline__ void shuf_layer(float4 (&v)[4], int lane, int base,
                                           const float* __restrict__ af,
                                           const float* __restrict__ bf) {
    const bool hi = (lane & M) != 0;
    #pragma unroll
    for (int j = 0; j < 4; ++j) {
        int c = base + (j << JSH) + (lane >> LSH);
        if constexpr (UNIF) c = __builtin_amdgcn_readfirstlane(c);
        const float a = af[c], b = bf[c];
        const float sb = hi ? -b : b;   // top: +b*partner ; bot: -b*partner
        v[j].x = fmaf(a, v[j].x, sb * pxor<M>(v[j].x, hi));
        v[j].y = fmaf(a, v[j].y, sb * pxor<M>(v[j].y, hi));
        v[j].z = fmaf(a, v[j].z, sb * pxor<M>(v[j].z, hi));
        v[j].w = fmaf(a, v[j].w, sb * pxor<M>(v[j].w, hi));
    }
}

__global__ __launch_bounds__(256, 7)
void bfly_kernel(const float* __restrict__ x,
                 const float* __restrict__ af,
                 const float* __restrict__ bf,
                 float* __restrict__ out) {
    const int lane = threadIdx.x & 63;
    const int q    = threadIdx.x >> 6;     // wave index = row quarter
    const size_t row = blockIdx.x;

    const float4* __restrict__ xr = reinterpret_cast<const float4*>(x + row * DIM) + q * 256;
    float4* __restrict__ orow     = reinterpret_cast<float4*>(out + row * DIM) + q * 256;

    __shared__ float4 xch[4][4][64];   // [wave][j][lane] = 16 KB

    float4 v[4];
    #pragma unroll
    for (int j = 0; j < 4; ++j) v[j] = xr[64 * j + lane];

    // ---- L0 (bs=1): pairs (x,y),(z,w); c0 = 512q + 128j + 2*lane, c0+1 ----
    #pragma unroll
    for (int j = 0; j < 4; ++j) {
        const int c = 512 * q + 128 * j + 2 * lane;
        float2 aa = *reinterpret_cast<const float2*>(af + c);
        float2 bb = *reinterpret_cast<const float2*>(bf + c);
        rot2(v[j].x, v[j].y, aa.x, bb.x);
        rot2(v[j].z, v[j].w, aa.y, bb.y);
    }

    // ---- L1 (bs=2): pairs (x,z),(y,w); c = 2048 + 256q + 64j + lane ----
    #pragma unroll
    for (int j = 0; j < 4; ++j) {
        const int c = 2048 + 256 * q + 64 * j + lane;
        const float a = af[c], b = bf[c];
        rot2(v[j].x, v[j].z, a, b);
        rot2(v[j].y, v[j].w, a, b);
    }

    // ---- L2..L7: cross-lane layers (all DPP/permlane VALU) ----
    shuf_layer< 1, 5, 1, false>(v, lane, 3072 + 128 * q, af, bf);  // bs=4
    shuf_layer< 2, 4, 2, false>(v, lane, 3584 +  64 * q, af, bf);  // bs=8
    shuf_layer< 4, 3, 3, false>(v, lane, 3840 +  32 * q, af, bf);  // bs=16
    shuf_layer< 8, 2, 4, false>(v, lane, 3968 +  16 * q, af, bf);  // bs=32
    shuf_layer<16, 1, 5, false>(v, lane, 4032 +   8 * q, af, bf);  // bs=64
    shuf_layer<32, 0, 6, true >(v, lane, 4064 +   4 * q, af, bf);  // bs=128 (uniform)

    // ---- L8 (bs=256): pairs (0,1),(2,3); c = 4080 + 2q + k (uniform -> s_load) ----
    #pragma unroll
    for (int k = 0; k < 2; ++k) {
        const int c = __builtin_amdgcn_readfirstlane(4080 + 2 * q + k);
        const float a = af[c], b = bf[c];
        rot2(v[2*k].x, v[2*k+1].x, a, b);
        rot2(v[2*k].y, v[2*k+1].y, a, b);
        rot2(v[2*k].z, v[2*k+1].z, a, b);
        rot2(v[2*k].w, v[2*k+1].w, a, b);
    }
    // ---- L9 (bs=512): pairs (0,2),(1,3); c = 4088 + q (uniform) ----
    {
        const int c = __builtin_amdgcn_readfirstlane(4088 + q);
        const float a = af[c], b = bf[c];
        #pragma unroll
        for (int j = 0; j < 2; ++j) {
            rot2(v[j].x, v[j+2].x, a, b);
            rot2(v[j].y, v[j+2].y, a, b);
            rot2(v[j].z, v[j+2].z, a, b);
            rot2(v[j].w, v[j+2].w, a, b);
        }
    }

    // ---- L10+L11 fused: one 4-source combine across waves, ONE barrier ----
    // (R3/R6/R9-verified algebra.) u = w0*v + w1*v(q^1) + w2*v(q^2) + w3*v(q^3).
    {
        const float a0 = af[4092], b0 = bf[4092];   // e11=0  (constant idx -> s_load)
        const float a1 = af[4093], b1 = bf[4093];   // e11=1
        const float A  = af[4094], B  = bf[4094];
        const int h11 = q >> 1, h10 = q & 1;
        const float aO = h11 ? a1 : a0, bO = h11 ? b1 : b0;
        const float aX = h11 ? a0 : a1, bX = h11 ? b0 : b1;
        const float phX = h11 ? -B : B;
        const float w0 = A * aO;
        const float w1 = A * (h10 ? -bO : bO);
        const float w2 = phX * aX;
        const float w3 = phX * (h10 ? -bX : bX);
        const int q1 = q ^ 1, q2 = q ^ 2, q3 = q ^ 3;

        #pragma unroll
        for (int j = 0; j < 4; ++j) xch[q][j][lane] = v[j];
        __syncthreads();
        #pragma unroll
        for (int j = 0; j < 4; ++j) {
            float4 e1 = xch[q1][j][lane];
            float4 e2 = xch[q2][j][lane];
            float4 e3 = xch[q3][j][lane];
            float4 a;
            a.x = fmaf(w3, e3.x, fmaf(w2, e2.x, fmaf(w1, e1.x, w0 * v[j].x)));
            a.y = fmaf(w3, e3.y, fmaf(w2, e2.y, fmaf(w1, e1.y, w0 * v[j].y)));
            a.z = fmaf(w3, e3.z, fmaf(w2, e2.z, fmaf(w1, e1.z, w0 * v[j].z)));
            a.w = fmaf(w3, e3.w, fmaf(w2, e2.w, fmaf(w1, e1.w, w0 * v[j].w)));
            v[j] = a;
        }
    }

    // ---- Store: nontemporal, coalesced 16B/lane ----
    #pragma unroll
    for (int j = 0; j < 4; ++j) store_nt4(&orow[64 * j + lane], v[j]);
}

extern "C" void kernel_launch(void* const* d_in, const int* in_sizes, int n_in,
                              void* d_out, int out_size, void* d_ws, size_t ws_size,
                              hipStream_t stream) {
    const float* x  = (const float*)d_in[0];
    const float* af = (const float*)d_in[1];
    const float* bf = (const float*)d_in[2];
    float* out      = (float*)d_out;
    (void)d_ws; (void)ws_size;

    hipLaunchKernelGGL(bfly_kernel, dim3(BATCH), dim3(256), 0, stream,
                       x, af, bf, out);
}